// Round 3
// baseline (270.898 us; speedup 1.0000x reference)
//
#include <hip/hip_runtime.h>
#include <hip/hip_bf16.h>

#define EPS 1e-5f

// ---------- bf16 helpers (RNE) ----------
__device__ __forceinline__ unsigned short f2bf(float f) {
    unsigned int u = __builtin_bit_cast(unsigned int, f);
    unsigned int r = u + 0x7FFFu + ((u >> 16) & 1u);
    return (unsigned short)(r >> 16);
}
__device__ __forceinline__ float bf2f(unsigned short b) {
    unsigned int u = ((unsigned int)b) << 16;
    return __builtin_bit_cast(float, u);
}
__device__ __forceinline__ unsigned int pack2bf(float lo, float hi) {
    return (unsigned int)f2bf(lo) | ((unsigned int)f2bf(hi) << 16);
}

typedef __attribute__((ext_vector_type(8))) short short8;
typedef __attribute__((ext_vector_type(4))) float floatx4;

// =====================================================================
// Kernel A: y = relu(bn(conv1x1(x)))  -> bf16 workspace
// Register-prefetch pipelined: next tile's global loads issue right
// after the post-stage barrier and overlap frag reads + MFMA.
// B-stage: float4 loads (2 adjacent k rows), packed ds_write_b32.
// =====================================================================
#define BM 128
#define BN 128
#define BK 32
#define SK 40

__global__ __launch_bounds__(256) void conv1x1_bn_relu(
    const float* __restrict__ x,
    const float* __restrict__ w,
    const float* __restrict__ cb,
    const float* __restrict__ gamma, const float* __restrict__ beta,
    const float* __restrict__ mean,  const float* __restrict__ var,
    unsigned short* __restrict__ y)
{
    const int nt  = blockIdx.x >> 1;
    const int mb  = blockIdx.x & 1;
    const int b   = blockIdx.z;
    const int tid = threadIdx.x;

    __shared__ unsigned short Al[BM * SK];
    __shared__ unsigned short Bl[BN * SK];
    __shared__ float s1[BM], u1[BM];

    const int m0 = mb * BM;
    const int p0 = nt * BN;

    if (tid < BM) {
        int o = m0 + tid;
        float s = gamma[o] * rsqrtf(var[o] + EPS);
        s1[tid] = s;
        u1[tid] = cb[o] * s + beta[o] - mean[o] * s;
    }

    const float* xb = x + (size_t)b * 256 * 10240;

    floatx4 acc[4][4];
#pragma unroll
    for (int i = 0; i < 4; i++)
#pragma unroll
        for (int j = 0; j < 4; j++) acc[i][j] = (floatx4)0.0f;

    const int lane = tid & 63;
    const int wv   = tid >> 6;
    const int wm   = (wv & 1) * 64;
    const int wn   = (wv >> 1) * 64;
    const int lm   = lane & 15;
    const int lq   = lane >> 4;

    // B-stage mapping: 2 adjacent k rows, 2 pixel groups
    const int kk2 = (tid & 15) * 2;    // 0..30
    const int pg0 = tid >> 4;          // 0..15  (and pg0+16)
    // A-stage mapping
    const int am0 = tid >> 3;          // row for it=0 (+32 per it)
    const int af4 = tid & 7;

    float4 Ar[4], Br[4];

    auto loadA = [&](int k0) {
#pragma unroll
        for (int it = 0; it < 4; it++) {
            int m = am0 + it * 32;
            Ar[it] = *reinterpret_cast<const float4*>(
                w + (size_t)(m0 + m) * 256 + k0 + af4 * 4);
        }
    };
    auto loadB = [&](int k0) {
        const float* base = xb + (size_t)(k0 + kk2) * 10240 + p0;
        Br[0] = *reinterpret_cast<const float4*>(base + 4 * pg0);
        Br[1] = *reinterpret_cast<const float4*>(base + 10240 + 4 * pg0);
        Br[2] = *reinterpret_cast<const float4*>(base + 4 * (pg0 + 16));
        Br[3] = *reinterpret_cast<const float4*>(base + 10240 + 4 * (pg0 + 16));
    };

    loadA(0);
    loadB(0);

    for (int k0 = 0; k0 < 256; k0 += BK) {
        __syncthreads();   // previous iteration's frag reads complete
        // ---- commit staged regs to LDS
#pragma unroll
        for (int it = 0; it < 4; it++) {
            int m = am0 + it * 32;
            *reinterpret_cast<ushort4*>(&Al[m * SK + af4 * 4]) =
                make_ushort4(f2bf(Ar[it].x), f2bf(Ar[it].y),
                             f2bf(Ar[it].z), f2bf(Ar[it].w));
        }
        {
            const float* r0 = reinterpret_cast<const float*>(&Br[0]);
            const float* r1 = reinterpret_cast<const float*>(&Br[1]);
            const float* r2 = reinterpret_cast<const float*>(&Br[2]);
            const float* r3 = reinterpret_cast<const float*>(&Br[3]);
#pragma unroll
            for (int i = 0; i < 4; i++) {
                *reinterpret_cast<unsigned int*>(&Bl[(4 * pg0 + i) * SK + kk2]) =
                    pack2bf(r0[i], r1[i]);
                *reinterpret_cast<unsigned int*>(&Bl[(4 * (pg0 + 16) + i) * SK + kk2]) =
                    pack2bf(r2[i], r3[i]);
            }
        }
        __syncthreads();
        // ---- prefetch next tile (overlaps frag reads + MFMA below)
        if (k0 + BK < 256) { loadA(k0 + BK); loadB(k0 + BK); }

        short8 af[4], bfr[4];
#pragma unroll
        for (int i = 0; i < 4; i++) {
            int m = wm + i * 16 + lm;
            af[i] = *reinterpret_cast<const short8*>(&Al[m * SK + lq * 8]);
        }
#pragma unroll
        for (int j = 0; j < 4; j++) {
            int n = wn + j * 16 + lm;
            bfr[j] = *reinterpret_cast<const short8*>(&Bl[n * SK + lq * 8]);
        }
#pragma unroll
        for (int i = 0; i < 4; i++)
#pragma unroll
            for (int j = 0; j < 4; j++)
                acc[i][j] = __builtin_amdgcn_mfma_f32_16x16x32_bf16(
                    af[i], bfr[j], acc[i][j], 0, 0, 0);
    }

    unsigned short* yb = y + (size_t)b * 256 * 10240;
#pragma unroll
    for (int i = 0; i < 4; i++) {
        int mo_base = wm + i * 16 + lq * 4;
#pragma unroll
        for (int j = 0; j < 4; j++) {
            int p = p0 + wn + j * 16 + lm;
#pragma unroll
            for (int r = 0; r < 4; r++) {
                int mo = mo_base + r;
                float v = acc[i][j][r] * s1[mo] + u1[mo];
                v = fmaxf(v, 0.0f);
                yb[(size_t)(m0 + mo) * 10240 + p] = f2bf(v);
            }
        }
    }
}

// =====================================================================
// Kernel B: strips of 40 cols, full 64 rows.
//  step1: per-thread 13 contiguous cols (no div, wrap only on edge strips)
//  step2: 2-row x 4-col tasks (8 LDS reads per 8 q)
//  step3: tid<160: 4x4 register-blocked outputs (18 reads per 16 out)
//         tid>=160: border fixup concurrently
// =====================================================================
#define YS 52
#define QS 52

__global__ __launch_bounds__(256) void refine_accum(
    const float* __restrict__ x,
    const unsigned short* __restrict__ y,
    const float* __restrict__ rw,
    const float* __restrict__ rb,
    const float* __restrict__ rg, const float* __restrict__ rbe,
    const float* __restrict__ rm, const float* __restrict__ rv,
    float* __restrict__ out)
{
    const int bi    = blockIdx.x;
    const int strip = bi & 3;
    const int c     = (bi >> 2) & 255;
    const int b     = bi >> 10;
    const int c0    = strip * 40;
    const int tid   = threadIdx.x;

    __shared__ float yt[64 * YS];   // col j <-> w = c0-5+j (mod 160)
    __shared__ float qt[64 * QS];   // col qc <-> w = c0-4+qc

    const size_t img = ((size_t)b * 256 + c) * 10240;
    const unsigned short* yp = y + img;

    float w9[9];
#pragma unroll
    for (int t = 0; t < 9; t++) w9[t] = rw[c * 9 + t];
    const float s2 = rg[c] * rsqrtf(rv[c] + EPS);
    const float u2 = rb[c] * s2 + rbe[c] - rm[c] * s2;

    // ---- step1: thread -> (row = tid>>2, 13 contiguous cols)
    {
        const int r  = tid >> 2;
        const int j0 = (tid & 3) * 13;
        const unsigned short* yrow = yp + r * 160;
        float* drow = &yt[r * YS + j0];
        const bool mayWrap = (c0 == 0) || (c0 == 120);
        if (!mayWrap) {
            const unsigned short* s = yrow + (c0 - 5 + j0);
#pragma unroll
            for (int i = 0; i < 13; i++) drow[i] = bf2f(s[i]);
        } else {
#pragma unroll
            for (int i = 0; i < 13; i++) {
                int gw = c0 - 5 + j0 + i;
                if (gw < 0) gw += 160; else if (gw >= 160) gw -= 160;
                drow[i] = bf2f(yrow[gw]);
            }
        }
    }
    __syncthreads();

    // ---- step2: q = relu(bn(circular conv3x3)), 2 rows x 4 cols per task
    for (int t = tid; t < 32 * 12; t += 256) {
        int rbk = t / 12, g = t - rbk * 12;
        int r0 = 2 * rbk, q0 = 4 * g;
        int ra = (r0 + 63) & 63, rd = (r0 + 2) & 63;
        float A[8], B[8], C[8], D[8];
        *reinterpret_cast<float4*>(&A[0]) = *reinterpret_cast<const float4*>(&yt[ra * YS + q0]);
        *reinterpret_cast<float4*>(&A[4]) = *reinterpret_cast<const float4*>(&yt[ra * YS + q0 + 4]);
        *reinterpret_cast<float4*>(&B[0]) = *reinterpret_cast<const float4*>(&yt[r0 * YS + q0]);
        *reinterpret_cast<float4*>(&B[4]) = *reinterpret_cast<const float4*>(&yt[r0 * YS + q0 + 4]);
        *reinterpret_cast<float4*>(&C[0]) = *reinterpret_cast<const float4*>(&yt[(r0 + 1) * YS + q0]);
        *reinterpret_cast<float4*>(&C[4]) = *reinterpret_cast<const float4*>(&yt[(r0 + 1) * YS + q0 + 4]);
        *reinterpret_cast<float4*>(&D[0]) = *reinterpret_cast<const float4*>(&yt[rd * YS + q0]);
        *reinterpret_cast<float4*>(&D[4]) = *reinterpret_cast<const float4*>(&yt[rd * YS + q0 + 4]);
        float4 qlo, qhi;
        float* ql = reinterpret_cast<float*>(&qlo);
        float* qh = reinterpret_cast<float*>(&qhi);
#pragma unroll
        for (int i = 0; i < 4; i++) {
            float z0 = w9[0] * A[i] + w9[1] * A[i + 1] + w9[2] * A[i + 2]
                     + w9[3] * B[i] + w9[4] * B[i + 1] + w9[5] * B[i + 2]
                     + w9[6] * C[i] + w9[7] * C[i + 1] + w9[8] * C[i + 2];
            float z1 = w9[0] * B[i] + w9[1] * B[i + 1] + w9[2] * B[i + 2]
                     + w9[3] * C[i] + w9[4] * C[i + 1] + w9[5] * C[i + 2]
                     + w9[6] * D[i] + w9[7] * D[i + 1] + w9[8] * D[i + 2];
            ql[i] = fmaxf(z0 * s2 + u2, 0.0f);
            qh[i] = fmaxf(z1 * s2 + u2, 0.0f);
        }
        *reinterpret_cast<float4*>(&qt[r0 * QS + q0]) = qlo;
        *reinterpret_cast<float4*>(&qt[(r0 + 1) * QS + q0]) = qhi;
    }
    __syncthreads();

    const float w1 = 0.80073740f, w2 = 0.41111229f, w3 = 0.13533528f;
    const float SCALE = 0.5f / (4.0f * (w1 + w2 + w3));

    if (tid < 160) {
        // ---- step3: 4 rows x 4 cols per thread
        const int rg4 = tid / 10, cg = tid - rg4 * 10;
        const int r0 = 4 * rg4;
        const int qb = 4 * cg + 4;      // qc of w0 = c0 + 4*cg
        const int w0 = c0 + 4 * cg;

        float V[10][4], L[4][4], R[4][4];
#pragma unroll
        for (int k = 0; k < 10; k++)
            *reinterpret_cast<float4*>(&V[k][0]) =
                *reinterpret_cast<const float4*>(&qt[((r0 - 3 + k + 64) & 63) * QS + qb]);
#pragma unroll
        for (int i = 0; i < 4; i++) {
            *reinterpret_cast<float4*>(&L[i][0]) =
                *reinterpret_cast<const float4*>(&qt[(r0 + i) * QS + qb - 4]);
            *reinterpret_cast<float4*>(&R[i][0]) =
                *reinterpret_cast<const float4*>(&qt[(r0 + i) * QS + qb + 4]);
        }
#pragma unroll
        for (int i = 0; i < 4; i++) {
            int r = r0 + i;
            size_t gidx = img + (size_t)r * 160 + w0;
            float4 xv = *reinterpret_cast<const float4*>(&x[gidx]);
            const float* xvp = reinterpret_cast<const float*>(&xv);
            float H[12];
#pragma unroll
            for (int j = 0; j < 4; j++) H[j]     = L[i][j];
#pragma unroll
            for (int j = 0; j < 4; j++) H[4 + j] = V[i + 3][j];
#pragma unroll
            for (int j = 0; j < 4; j++) H[8 + j] = R[i][j];
            float ov[4];
#pragma unroll
            for (int j = 0; j < 4; j++) {
                float vs = w1 * (V[i + 2][j] + V[i + 4][j])
                         + w2 * (V[i + 1][j] + V[i + 5][j])
                         + w3 * (V[i][j]     + V[i + 6][j]);
                float hs = w1 * (H[3 + j] + H[5 + j])
                         + w2 * (H[2 + j] + H[6 + j])
                         + w3 * (H[1 + j] + H[7 + j]);
                ov[j] = xvp[j] + SCALE * (vs + hs);
            }
            bool rowok = (r != 0) && (r != 63);
            if (rowok) {
                if (c0 == 0 && cg == 0) {
                    out[gidx + 1] = ov[1]; out[gidx + 2] = ov[2]; out[gidx + 3] = ov[3];
                } else if (c0 == 120 && cg == 9) {
                    out[gidx] = ov[0]; out[gidx + 1] = ov[1]; out[gidx + 2] = ov[2];
                } else {
                    *reinterpret_cast<float4*>(&out[gidx]) =
                        make_float4(ov[0], ov[1], ov[2], ov[3]);
                }
            }
        }
    } else {
        // ---- border fixup on threads 160..255 (concurrent with step3)
        const int SH[12] = {1, 2, 3, -1, -2, -3, 0, 0, 0, 0, 0, 0};
        const int SW[12] = {0, 0, 0, 0, 0, 0, -1, -2, -3, 1, 2, 3};
        const float WT[12] = {w1, w2, w3, w1, w2, w3, w1, w2, w3, w1, w2, w3};
        const bool edge = (c0 == 0) || (c0 == 120);
        const int nb = 80 + (edge ? 62 : 0);
#pragma unroll
        for (int it = 0; it < 2; it++) {
            int bidx = (tid - 160) + it * 96;
            if (bidx < nb) {
                int h, w;
                if (bidx < 40)      { h = 0;  w = c0 + bidx; }
                else if (bidx < 80) { h = 63; w = c0 + bidx - 40; }
                else                { h = bidx - 79; w = (c0 == 0) ? 0 : 159; }
                float mw[9];
#pragma unroll
                for (int dh = 0; dh < 3; dh++)
#pragma unroll
                    for (int dw = 0; dw < 3; dw++) {
                        int ih = h + dh - 1, iw = w + dw - 1;
                        mw[dh * 3 + dw] =
                            (ih >= 0 && ih < 64 && iw >= 0 && iw < 160) ? w9[dh * 3 + dw] : 0.0f;
                    }
                float accv = 0.0f;
#pragma unroll
                for (int s = 0; s < 12; s++) {
                    float conv = 0.0f;
#pragma unroll
                    for (int dh = 0; dh < 3; dh++)
#pragma unroll
                        for (int dw = 0; dw < 3; dw++) {
                            int row = (h + dh - 1 - SH[s]) & 63;
                            int jj  = (w - c0) + dw + 4 - SW[s];
                            conv += mw[dh * 3 + dw] * yt[row * YS + jj];
                        }
                    accv += WT[s] * fmaxf(conv * s2 + u2, 0.0f);
                }
                size_t gidx = img + (size_t)h * 160 + w;
                out[gidx] = x[gidx] + SCALE * accv;
            }
        }
    }
}

extern "C" void kernel_launch(void* const* d_in, const int* in_sizes, int n_in,
                              void* d_out, int out_size, void* d_ws, size_t ws_size,
                              hipStream_t stream) {
    const float* x      = (const float*)d_in[0];
    const float* conv_w = (const float*)d_in[1];
    const float* conv_b = (const float*)d_in[2];
    const float* bn_g   = (const float*)d_in[3];
    const float* bn_b   = (const float*)d_in[4];
    const float* bn_m   = (const float*)d_in[5];
    const float* bn_v   = (const float*)d_in[6];
    const float* ref_w  = (const float*)d_in[7];
    const float* ref_b  = (const float*)d_in[8];
    const float* rbn_g  = (const float*)d_in[9];
    const float* rbn_b  = (const float*)d_in[10];
    const float* rbn_m  = (const float*)d_in[11];
    const float* rbn_v  = (const float*)d_in[12];
    float* out          = (float*)d_out;
    unsigned short* y_ws = (unsigned short*)d_ws;

    conv1x1_bn_relu<<<dim3(160, 1, 8), 256, 0, stream>>>(
        x, conv_w, conv_b, bn_g, bn_b, bn_m, bn_v, y_ws);
    refine_accum<<<dim3(8 * 256 * 4), 256, 0, stream>>>(
        x, y_ws, ref_w, ref_b, rbn_g, rbn_b, rbn_m, rbn_v, out);
}